// Round 5
// baseline (333.958 us; speedup 1.0000x reference)
//
#include <hip/hip_runtime.h>
#include <hip/hip_bf16.h>

#define N_NODES 4096
#define CIN     128
#define COUT    256
#define WIDTH   64
#define KDIM    16
#define SLOPE   0.1f
#define WSLOPE  0.2f
#define BN_EPS  1e-5f

__device__ __forceinline__ float lrelu(float x, float s) { return x > 0.f ? x : s * x; }

// Load a "float input" element: f32 (per reference) or bf16; runtime flag.
__device__ __forceinline__ float ldf(const void* p, size_t i, int isf32) {
  return isf32 ? ((const float*)p)[i]
               : __bfloat162float(((const __hip_bfloat16*)p)[i]);
}

// ---- dtype sniff: reinterpret x as bf16; f32 data shows huge/NaN values ----
__global__ void sniff_kernel(const void* x, int* flag) {
  int t = threadIdx.x;
  const __hip_bfloat16* p = (const __hip_bfloat16*)x;
  int bad = 0;
  for (int i = t; i < 256; i += 64) {
    float v = __bfloat162float(p[i]);
    if (!(fabsf(v) < 1e4f)) bad = 1;
  }
  unsigned long long m = __ballot(bad);
  if (t == 0) *flag = (m != 0ull) ? 1 : 0;   // 1 => underlying data is f32
}

// ---------------- column mean / biased var over M rows (input array) --------
__global__ __launch_bounds__(256) void col_stats_in_kernel(
    const void* __restrict__ X, int M, int C, const int* __restrict__ flagp,
    float* __restrict__ mean, float* __restrict__ var) {
  int isf = *flagp;
  int c = blockIdx.x;
  int t = threadIdx.x;
  float s = 0.f, sq = 0.f;
  for (int r = t; r < M; r += 256) {
    float v = ldf(X, (size_t)r * C + c, isf);
    s += v; sq += v * v;
  }
  __shared__ float ls[256], lq[256];
  ls[t] = s; lq[t] = sq; __syncthreads();
  for (int st = 128; st > 0; st >>= 1) {
    if (t < st) { ls[t] += ls[t + st]; lq[t] += lq[t + st]; }
    __syncthreads();
  }
  if (t == 0) {
    float m = ls[0] / M;
    mean[c] = m;
    var[c] = lq[0] / M - m * m;
  }
}

// ---------------- same but over a f32 workspace array ----------------
__global__ __launch_bounds__(256) void col_stats_f32_kernel(
    const float* __restrict__ X, int M, int C,
    float* __restrict__ mean, float* __restrict__ var) {
  int c = blockIdx.x;
  int t = threadIdx.x;
  float s = 0.f, sq = 0.f;
  for (int r = t; r < M; r += 256) {
    float v = X[(size_t)r * C + c];
    s += v; sq += v * v;
  }
  __shared__ float ls[256], lq[256];
  ls[t] = s; lq[t] = sq; __syncthreads();
  for (int st = 128; st > 0; st >>= 1) {
    if (t < st) { ls[t] += ls[t + st]; lq[t] += lq[t + st]; }
    __syncthreads();
  }
  if (t == 0) {
    float m = ls[0] / M;
    mean[c] = m;
    var[c] = lq[0] / M - m * m;
  }
}

// -------- A = lrelu(bn_id(x)), B = lrelu(bn_in(x)) (shared x stats) --------
__global__ __launch_bounds__(256) void act_ab_kernel(
    const void* __restrict__ x, const int* __restrict__ flagp,
    const float* __restrict__ mean, const float* __restrict__ var,
    const void* __restrict__ gA, const void* __restrict__ bA,
    const void* __restrict__ gB, const void* __restrict__ bB,
    float* __restrict__ A, float* __restrict__ B) {
  int isf = *flagp;
  int idx = blockIdx.x * 256 + threadIdx.x;      // over N*CIN
  int c = idx & (CIN - 1);
  float xn = (ldf(x, idx, isf) - mean[c]) * rsqrtf(var[c] + BN_EPS);
  A[idx] = lrelu(xn * ldf(gA, c, isf) + ldf(bA, c, isf), SLOPE);
  B[idx] = lrelu(xn * ldf(gB, c, isf) + ldf(bB, c, isf), SLOPE);
}

// -------- ident = A[4096,128] @ id_W[128,256]; 8 rows/block, col=thread -----
__global__ __launch_bounds__(256) void gemm_cout_kernel(
    const float* __restrict__ A, const void* __restrict__ W,
    const int* __restrict__ flagp, float* __restrict__ C) {
  int isf = *flagp;
  int t = threadIdx.x;
  int n0 = blockIdx.x * 8;
  __shared__ float at[8 * CIN];               // 4 KB
  ((float4*)at)[t] = ((const float4*)(A + (size_t)n0 * CIN))[t];
  __syncthreads();
  float acc[8];
#pragma unroll
  for (int r = 0; r < 8; r++) acc[r] = 0.f;
  for (int k = 0; k < CIN; k++) {
    float w = ldf(W, (size_t)k * COUT + t, isf);
#pragma unroll
    for (int r = 0; r < 8; r++) acc[r] += at[r * CIN + k] * w;
  }
#pragma unroll
  for (int r = 0; r < 8; r++) C[(size_t)(n0 + r) * COUT + t] = acc[r];
}

// -------- hpre = B[4096,128] @ in_W[128,64]; 8 rows/block, wave -> 2 rows ---
__global__ __launch_bounds__(256) void gemm_w64_kernel(
    const float* __restrict__ A, const void* __restrict__ W,
    const int* __restrict__ flagp, float* __restrict__ C) {
  int isf = *flagp;
  int t = threadIdx.x;
  int j = t & 63;
  int g = t >> 6;                              // wave id -> rows 2g, 2g+1
  int n0 = blockIdx.x * 8;
  __shared__ float at[8 * CIN];                // 4 KB
  ((float4*)at)[t] = ((const float4*)(A + (size_t)n0 * CIN))[t];
  __syncthreads();
  float a0 = 0.f, a1 = 0.f;
  for (int k = 0; k < CIN; k++) {
    float w = ldf(W, (size_t)k * WIDTH + j, isf);
    a0 += at[(2 * g) * CIN + k] * w;
    a1 += at[(2 * g + 1) * CIN + k] * w;
  }
  C[(size_t)(n0 + 2 * g) * WIDTH + j] = a0;
  C[(size_t)(n0 + 2 * g + 1) * WIDTH + j] = a1;
}

// -------- Y = lrelu(bn(X)) elementwise on ws f32, C channels pow2 --------
__global__ __launch_bounds__(256) void bnleaky_kernel(
    const float* __restrict__ X, const float* __restrict__ mean,
    const float* __restrict__ var,
    const void* __restrict__ g, const void* __restrict__ b,
    const int* __restrict__ flagp, float* __restrict__ Y, int Cmask) {
  int isf = *flagp;
  int idx = blockIdx.x * 256 + threadIdx.x;
  int c = idx & Cmask;
  float xn = (X[idx] - mean[c]) * rsqrtf(var[c] + BN_EPS);
  Y[idx] = lrelu(xn * ldf(g, c, isf) + ldf(b, c, isf), SLOPE);
}

// -------- fused convert of the 3 branch weight matrices -> f32 ws --------
__global__ __launch_bounds__(256) void cvt3_kernel(
    const void* __restrict__ W1, const void* __restrict__ W2,
    const void* __restrict__ W3, const int* __restrict__ flagp,
    float* __restrict__ dst) {   // dst = Wf1|Wf2|Wf3 contiguous (32K|16K|16K)
  int isf = *flagp;
  int i = blockIdx.x * 256 + threadIdx.x;   // 0..65535
  float v;
  if (i < 32768)      v = ldf(W1, i, isf);
  else if (i < 49152) v = ldf(W2, i - 32768, isf);
  else                v = ldf(W3, i - 49152, isf);
  dst[i] = v;
}

// -------- rowptr[b][n] = lower_bound(dst_b, n); rowptr[b][N] = E_b --------
__global__ __launch_bounds__(256) void rowptr_kernel(
    const int* __restrict__ d1, int E1, const int* __restrict__ d2, int E2,
    const int* __restrict__ d3, int E3, int* __restrict__ rp) {
  int t = blockIdx.x * 256 + threadIdx.x;   // 3 * (N+1)
  if (t >= 3 * (N_NODES + 1)) return;
  int b = t / (N_NODES + 1);
  int n = t % (N_NODES + 1);
  const int* d = (b == 0) ? d1 : (b == 1) ? d2 : d3;
  int E = (b == 0) ? E1 : (b == 1) ? E2 : E3;
  int lo = 0, hi = E;
  if (n >= N_NODES) lo = E;
  else {
    while (lo < hi) { int mid = (lo + hi) >> 1; if (d[mid] < n) lo = mid + 1; else hi = mid; }
  }
  rp[(size_t)b * (N_NODES + 1) + n] = lo;
}

// -------- fused per-edge gate weights for all 3 branches --------
struct EdgeParams {
  const int* src; const int* dst;
  const void* Ws; const void* bs;
  float* wbuf; int E; float inv_r; int hl;
};

__global__ __launch_bounds__(256) void edge_w3_kernel(
    EdgeParams p0, EdgeParams p1, EdgeParams p2,
    const void* __restrict__ pos, const void* __restrict__ ori,
    const int* __restrict__ seq, const int* __restrict__ flagp) {
  int b = blockIdx.y;
  EdgeParams p = (b == 0) ? p0 : (b == 1) ? p1 : p2;
  int isf = *flagp;
  int e = blockIdx.x * 256 + threadIdx.x;
  if (e >= p.E) return;
  int j = p.src[e], i = p.dst[e];
  float px = ldf(pos, j * 3 + 0, isf) - ldf(pos, i * 3 + 0, isf);
  float py = ldf(pos, j * 3 + 1, isf) - ldf(pos, i * 3 + 1, isf);
  float pz = ldf(pos, j * 3 + 2, isf) - ldf(pos, i * 3 + 2, isf);
  float dist = sqrtf(px * px + py * py + pz * pz);
  float inv = 1.0f / (dist + 1e-9f);
  float dx = px * inv, dy = py * inv, dz = pz * inv;
  float fi[9], fj[9];
#pragma unroll
  for (int t = 0; t < 9; t++) {
    fi[t] = ldf(ori, (size_t)i * 9 + t, isf);
    fj[t] = ldf(ori, (size_t)j * 9 + t, isf);
  }
  float feat[7];
  feat[0] = dist * p.inv_r;
  feat[1] = fi[0] * dx + fi[1] * dy + fi[2] * dz;
  feat[2] = fi[3] * dx + fi[4] * dy + fi[5] * dz;
  feat[3] = fi[6] * dx + fi[7] * dy + fi[8] * dz;
  feat[4] = fi[0] * fj[0] + fi[1] * fj[1] + fi[2] * fj[2];
  feat[5] = fi[3] * fj[3] + fi[4] * fj[4] + fi[5] * fj[5];
  feat[6] = fi[6] * fj[6] + fi[7] * fj[7] + fi[8] * fj[8];
  int d = seq[j] - seq[i];
  d = d < -p.hl ? -p.hl : (d > p.hl ? p.hl : d);
  int bin = d + p.hl;
  const size_t Wo = (size_t)bin * 7 * KDIM;
  const size_t bo = (size_t)bin * KDIM;
#pragma unroll
  for (int k = 0; k < KDIM; k++) {
    float a = ldf(p.bs, bo + k, isf);
#pragma unroll
    for (int c = 0; c < 7; c++) a += feat[c] * ldf(p.Ws, Wo + c * KDIM + k, isf);
    p.wbuf[(size_t)e * KDIM + k] = lrelu(a, WSLOPE);
  }
}

// -------- fused per-node aggregation + branch GEMM, all 3 branches --------
// 8 nodes per block; wave wv serially owns nodes 2wv, 2wv+1 (no cross-wave
// combine). agg staged in LDS (row pad 4 words). Epilogue: thread ->
// (node r, col o); agg reads broadcast, Wf reads coalesced & shared -> Wf
// traffic amortized over 8 nodes.
struct AggParams {
  const int* src; const float* wbuf; const float* Wf;
  int O; int coloff;
};

#define AGG_LD (KDIM * WIDTH + 4)   // 1028: +4 breaks same-bank row aliasing

__global__ __launch_bounds__(256) void agg3_kernel(
    AggParams p0, AggParams p1, AggParams p2,
    const int* __restrict__ rowptr,
    const float* __restrict__ h, float* __restrict__ cat) {
  int b = blockIdx.y;
  AggParams p = (b == 0) ? p0 : (b == 1) ? p1 : p2;
  int n0 = blockIdx.x * 8;
  int t = threadIdx.x;
  int lane = t & 63;
  int wv = t >> 6;

  __shared__ float agg8[8 * AGG_LD];   // ~32.1 KB
  const int* rp = rowptr + (size_t)b * (N_NODES + 1);

  for (int pi = 0; pi < 2; pi++) {
    int n = n0 + 2 * wv + pi;
    int start = rp[n], end = rp[n + 1];
    float acc[KDIM];
#pragma unroll
    for (int k = 0; k < KDIM; k++) acc[k] = 0.f;
    int jn = (start < end) ? p.src[start] : 0;
    for (int e = start; e < end; e++) {
      int j = jn;
      if (e + 1 < end) jn = p.src[e + 1];          // prefetch gather index
      float hj = h[(size_t)j * WIDTH + lane];
      const float4* w4 = (const float4*)(p.wbuf + (size_t)e * KDIM);
      float4 w0 = w4[0], w1 = w4[1], w2 = w4[2], w3 = w4[3];
      acc[0]  += w0.x * hj; acc[1]  += w0.y * hj; acc[2]  += w0.z * hj; acc[3]  += w0.w * hj;
      acc[4]  += w1.x * hj; acc[5]  += w1.y * hj; acc[6]  += w1.z * hj; acc[7]  += w1.w * hj;
      acc[8]  += w2.x * hj; acc[9]  += w2.y * hj; acc[10] += w2.z * hj; acc[11] += w2.w * hj;
      acc[12] += w3.x * hj; acc[13] += w3.y * hj; acc[14] += w3.z * hj; acc[15] += w3.w * hj;
    }
    float* arow = agg8 + (size_t)(2 * wv + pi) * AGG_LD;
#pragma unroll
    for (int k = 0; k < KDIM; k++) arow[k * WIDTH + lane] = acc[k];
  }
  __syncthreads();

  // epilogue: out[n0+r][o] = sum_i agg[r][i] * Wf[i*O + o]
  int O = p.O;
  int o = t & (O - 1);
  int g = t / O;
  int r, kbeg, kend;
  if (O == 32) { r = g; kbeg = 0; kend = KDIM * WIDTH; }        // 8 groups = 8 nodes
  else { r = g >> 1; kbeg = (g & 1) * 512; kend = kbeg + 512; } // 16 groups: node + K-half
  const float* arow = agg8 + (size_t)r * AGG_LD;
  const float* wf = p.Wf;
  float part = 0.f;
  for (int i = kbeg; i < kend; i += 4) {
    float4 a = *(const float4*)(arow + i);
    part += a.x * wf[(size_t)(i + 0) * O + o];
    part += a.y * wf[(size_t)(i + 1) * O + o];
    part += a.z * wf[(size_t)(i + 2) * O + o];
    part += a.w * wf[(size_t)(i + 3) * O + o];
  }
  if (O == 16) part += __shfl_xor(part, 16, 64);   // combine K-halves (g pairs)
  if (O == 32 || ((t >> 4) & 1) == 0)
    cat[(size_t)(n0 + r) * WIDTH + p.coloff + o] = part;
}

// -------- out = lrelu(bn(cat)) @ outW + identity; 8 nodes/block ------------
__global__ __launch_bounds__(256) void final_kernel(
    const float* __restrict__ cat, const float* __restrict__ mean,
    const float* __restrict__ var,
    const void* __restrict__ g, const void* __restrict__ b,
    const void* __restrict__ outW, const int* __restrict__ flagp,
    const float* __restrict__ identity, void* __restrict__ out) {
  int isf = *flagp;
  int t = threadIdx.x;   // 256 = COUT; one output column per thread
  int n0 = blockIdx.x * 8;
  __shared__ float cn8[8 * WIDTH];   // 2 KB
#pragma unroll
  for (int s = 0; s < 2; s++) {
    int ii = s * 256 + t;            // 0..511
    int r = ii >> 6, k = ii & 63;
    float xn = (cat[(size_t)(n0 + r) * WIDTH + k] - mean[k]) * rsqrtf(var[k] + BN_EPS);
    cn8[ii] = lrelu(xn * ldf(g, k, isf) + ldf(b, k, isf), SLOPE);
  }
  __syncthreads();
  float acc[8];
#pragma unroll
  for (int r = 0; r < 8; r++) acc[r] = identity[(size_t)(n0 + r) * COUT + t];
  for (int k = 0; k < WIDTH; k++) {
    float w = ldf(outW, (size_t)k * COUT + t, isf);
#pragma unroll
    for (int r = 0; r < 8; r++) acc[r] += cn8[r * WIDTH + k] * w;
  }
#pragma unroll
  for (int r = 0; r < 8; r++) {
    size_t oidx = (size_t)(n0 + r) * COUT + t;
    if (isf) ((float*)out)[oidx] = acc[r];
    else     ((__hip_bfloat16*)out)[oidx] = __float2bfloat16(acc[r]);
  }
}

extern "C" void kernel_launch(void* const* d_in, const int* in_sizes, int n_in,
                              void* d_out, int out_size, void* d_ws, size_t ws_size,
                              hipStream_t stream) {
  const void* x    = d_in[0];
  const void* pos  = d_in[1];
  const void* ori  = d_in[2];
  const int* seq  = (const int*)d_in[3];
  const int* src1 = (const int*)d_in[5];  const int* dst1 = (const int*)d_in[6];
  const int* src2 = (const int*)d_in[7];  const int* dst2 = (const int*)d_in[8];
  const int* src3 = (const int*)d_in[9];  const int* dst3 = (const int*)d_in[10];
  const void* id_g  = d_in[11]; const void* id_b  = d_in[12]; const void* id_W = d_in[13];
  const void* in_g  = d_in[14]; const void* in_b  = d_in[15]; const void* in_W = d_in[16];
  const void* mid_g = d_in[17]; const void* mid_b = d_in[18];
  const void* Ws1   = d_in[19]; const void* bs1   = d_in[20]; const void* W1   = d_in[21];
  const void* Ws2   = d_in[22]; const void* bs2   = d_in[23]; const void* W2   = d_in[24];
  const void* Ws3   = d_in[25]; const void* bs3   = d_in[26]; const void* W3   = d_in[27];
  const void* out_g = d_in[28]; const void* out_b = d_in[29]; const void* out_W = d_in[30];

  const int E1 = in_sizes[5], E2 = in_sizes[7], E3 = in_sizes[9];

  float* wsp = (float*)d_ws;
  size_t off = 0;
  auto alloc = [&](size_t n) { float* p = wsp + off; off += (n + 63) & ~(size_t)63; return p; };
  int*   flag  = (int*)alloc(64);
  float* meanx = alloc(CIN);   float* varx = alloc(CIN);
  float* meanh = alloc(WIDTH); float* varh = alloc(WIDTH);
  float* meanc = alloc(WIDTH); float* varc = alloc(WIDTH);
  float* A     = alloc((size_t)N_NODES * CIN);
  float* B     = alloc((size_t)N_NODES * CIN);
  float* ident = alloc((size_t)N_NODES * COUT);
  float* hpre  = alloc((size_t)N_NODES * WIDTH);
  float* hbuf  = alloc((size_t)N_NODES * WIDTH);
  float* catb  = alloc((size_t)N_NODES * WIDTH);
  float* Wf1   = alloc(1024 * 32);        // contiguous: Wf1|Wf2|Wf3
  float* Wf2   = alloc(1024 * 16);
  float* Wf3   = alloc(1024 * 16);
  int*   rowp  = (int*)alloc(3 * (N_NODES + 1));
  float* w1    = alloc((size_t)E1 * KDIM);
  float* w2    = alloc((size_t)E2 * KDIM);
  float* w3    = alloc((size_t)E3 * KDIM);
  (void)ws_size; (void)n_in; (void)out_size;

  // 0. dtype sniff
  sniff_kernel<<<1, 64, 0, stream>>>(x, flag);
  // 1. stats of x (shared by id/in BN)
  col_stats_in_kernel<<<CIN, 256, 0, stream>>>(x, N_NODES, CIN, flag, meanx, varx);
  // 2. A/B activations
  act_ab_kernel<<<(N_NODES * CIN) / 256, 256, 0, stream>>>(x, flag, meanx, varx, id_g, id_b, in_g, in_b, A, B);
  // 3. identity = A @ id_W ; h_pre = B @ in_W (8 rows/block, W amortized)
  gemm_cout_kernel<<<N_NODES / 8, 256, 0, stream>>>(A, id_W, flag, ident);
  gemm_w64_kernel<<<N_NODES / 8, 256, 0, stream>>>(B, in_W, flag, hpre);
  // 4. mid BN stats + activation -> h
  col_stats_f32_kernel<<<WIDTH, 256, 0, stream>>>(hpre, N_NODES, WIDTH, meanh, varh);
  bnleaky_kernel<<<(N_NODES * WIDTH) / 256, 256, 0, stream>>>(hpre, meanh, varh, mid_g, mid_b, flag, hbuf, WIDTH - 1);
  // 5. branch GEMM weights -> f32 (fused), rowptr (fused)
  cvt3_kernel<<<65536 / 256, 256, 0, stream>>>(W1, W2, W3, flag, Wf1);
  rowptr_kernel<<<(3 * (N_NODES + 1) + 255) / 256, 256, 0, stream>>>(dst1, E1, dst2, E2, dst3, E3, rowp);
  // 6. per-edge gate weights (fused over branches)
  EdgeParams ep0{src1, dst1, Ws1, bs1, w1, E1, 1.0f / 2.70f, 2};
  EdgeParams ep1{src2, dst2, Ws2, bs2, w2, E2, 1.0f / 1.80f, 3};
  EdgeParams ep2{src3, dst3, Ws3, bs3, w3, E3, 1.0f / 1.35f, 5};
  int maxE = E1 > E2 ? (E1 > E3 ? E1 : E3) : (E2 > E3 ? E2 : E3);
  edge_w3_kernel<<<dim3((maxE + 255) / 256, 3), 256, 0, stream>>>(ep0, ep1, ep2, pos, ori, seq, flag);
  // 7. fused per-node aggregation + branch GEMMs -> cat (8 nodes/block)
  AggParams ap0{src1, w1, Wf1, 32, 0};
  AggParams ap1{src2, w2, Wf2, 16, 32};
  AggParams ap2{src3, w3, Wf3, 16, 48};
  agg3_kernel<<<dim3(N_NODES / 8, 3), 256, 0, stream>>>(ap0, ap1, ap2, rowp, hbuf, catb);
  // 8. out BN stats + final GEMM + residual (8 nodes/block)
  col_stats_f32_kernel<<<WIDTH, 256, 0, stream>>>(catb, N_NODES, WIDTH, meanc, varc);
  final_kernel<<<N_NODES / 8, 256, 0, stream>>>(catb, meanc, varc, out_g, out_b, out_W, flag, ident, d_out);
}

// Round 6
// 271.113 us; speedup vs baseline: 1.2318x; 1.2318x over previous
//
#include <hip/hip_runtime.h>
#include <hip/hip_bf16.h>

#define N_NODES 4096
#define CIN     128
#define COUT    256
#define WIDTH   64
#define KDIM    16
#define SLOPE   0.1f
#define WSLOPE  0.2f
#define BN_EPS  1e-5f

typedef float float4u __attribute__((ext_vector_type(4), aligned(4)));

__device__ __forceinline__ float lrelu(float x, float s) { return x > 0.f ? x : s * x; }

// Load a "float input" element: f32 (per reference) or bf16; runtime flag.
__device__ __forceinline__ float ldf(const void* p, size_t i, int isf32) {
  return isf32 ? ((const float*)p)[i]
               : __bfloat162float(((const __hip_bfloat16*)p)[i]);
}

// ---- dtype sniff: reinterpret x as bf16; f32 data shows huge/NaN values ----
__global__ void sniff_kernel(const void* x, int* flag) {
  int t = threadIdx.x;
  const __hip_bfloat16* p = (const __hip_bfloat16*)x;
  int bad = 0;
  for (int i = t; i < 256; i += 64) {
    float v = __bfloat162float(p[i]);
    if (!(fabsf(v) < 1e4f)) bad = 1;
  }
  unsigned long long m = __ballot(bad);
  if (t == 0) *flag = (m != 0ull) ? 1 : 0;   // 1 => underlying data is f32
}

// ---- column stats, 4 channels per block, coalesced float4 reads ----
__global__ __launch_bounds__(256) void col_stats4_in_kernel(
    const void* __restrict__ X, const int* __restrict__ flagp,
    float* __restrict__ mean, float* __restrict__ var) {   // C=CIN, M=N_NODES
  int isf = *flagp;
  int cg = blockIdx.x;                  // channel group of 4
  int t = threadIdx.x, lane = t & 63, wv = t >> 6;
  float s[4] = {0.f, 0.f, 0.f, 0.f}, q[4] = {0.f, 0.f, 0.f, 0.f};
  for (int r = t; r < N_NODES; r += 256) {
    float v[4];
    if (isf) {
      float4u a = *(const float4u*)((const float*)X + (size_t)r * CIN + cg * 4);
      v[0] = a.x; v[1] = a.y; v[2] = a.z; v[3] = a.w;
    } else {
      const __hip_bfloat16* p = (const __hip_bfloat16*)X + (size_t)r * CIN + cg * 4;
#pragma unroll
      for (int i = 0; i < 4; i++) v[i] = __bfloat162float(p[i]);
    }
#pragma unroll
    for (int i = 0; i < 4; i++) { s[i] += v[i]; q[i] += v[i] * v[i]; }
  }
#pragma unroll
  for (int m = 1; m < 64; m <<= 1) {
#pragma unroll
    for (int i = 0; i < 4; i++) { s[i] += __shfl_xor(s[i], m, 64); q[i] += __shfl_xor(q[i], m, 64); }
  }
  __shared__ float rs[4][4], rq[4][4];
  if (lane == 0) {
#pragma unroll
    for (int i = 0; i < 4; i++) { rs[wv][i] = s[i]; rq[wv][i] = q[i]; }
  }
  __syncthreads();
  if (t < 4) {
    float S = rs[0][t] + rs[1][t] + rs[2][t] + rs[3][t];
    float Q = rq[0][t] + rq[1][t] + rq[2][t] + rq[3][t];
    float m = S / N_NODES;
    mean[cg * 4 + t] = m;
    var[cg * 4 + t] = Q / N_NODES - m * m;
  }
}

__global__ __launch_bounds__(256) void col_stats4_f32_kernel(
    const float* __restrict__ X, int C,
    float* __restrict__ mean, float* __restrict__ var) {   // M=N_NODES
  int cg = blockIdx.x;
  int t = threadIdx.x, lane = t & 63, wv = t >> 6;
  float s[4] = {0.f, 0.f, 0.f, 0.f}, q[4] = {0.f, 0.f, 0.f, 0.f};
  for (int r = t; r < N_NODES; r += 256) {
    float4u a = *(const float4u*)(X + (size_t)r * C + cg * 4);
    float v[4] = {a.x, a.y, a.z, a.w};
#pragma unroll
    for (int i = 0; i < 4; i++) { s[i] += v[i]; q[i] += v[i] * v[i]; }
  }
#pragma unroll
  for (int m = 1; m < 64; m <<= 1) {
#pragma unroll
    for (int i = 0; i < 4; i++) { s[i] += __shfl_xor(s[i], m, 64); q[i] += __shfl_xor(q[i], m, 64); }
  }
  __shared__ float rs[4][4], rq[4][4];
  if (lane == 0) {
#pragma unroll
    for (int i = 0; i < 4; i++) { rs[wv][i] = s[i]; rq[wv][i] = q[i]; }
  }
  __syncthreads();
  if (t < 4) {
    float S = rs[0][t] + rs[1][t] + rs[2][t] + rs[3][t];
    float Q = rq[0][t] + rq[1][t] + rq[2][t] + rq[3][t];
    float m = S / N_NODES;
    mean[cg * 4 + t] = m;
    var[cg * 4 + t] = Q / N_NODES - m * m;
  }
}

// -------- A = lrelu(bn_id(x)), B = lrelu(bn_in(x)) (shared x stats) --------
__global__ __launch_bounds__(256) void act_ab_kernel(
    const void* __restrict__ x, const int* __restrict__ flagp,
    const float* __restrict__ mean, const float* __restrict__ var,
    const void* __restrict__ gA, const void* __restrict__ bA,
    const void* __restrict__ gB, const void* __restrict__ bB,
    float* __restrict__ A, float* __restrict__ B) {
  int isf = *flagp;
  int idx = blockIdx.x * 256 + threadIdx.x;      // over N*CIN
  int c = idx & (CIN - 1);
  float xn = (ldf(x, idx, isf) - mean[c]) * rsqrtf(var[c] + BN_EPS);
  A[idx] = lrelu(xn * ldf(gA, c, isf) + ldf(bA, c, isf), SLOPE);
  B[idx] = lrelu(xn * ldf(gB, c, isf) + ldf(bB, c, isf), SLOPE);
}

// -------- ident = A[4096,128] @ id_W[128,256]; 4 rows/block --------
__global__ __launch_bounds__(256) void gemm_cout_kernel(
    const float* __restrict__ A, const void* __restrict__ W,
    const int* __restrict__ flagp, float* __restrict__ C) {
  int isf = *flagp;
  int t = threadIdx.x;
  int n0 = blockIdx.x * 4;
  __shared__ float at[4 * CIN];               // 2 KB
  if (t < 128) ((float4*)at)[t] = ((const float4*)(A + (size_t)n0 * CIN))[t];
  __syncthreads();
  float acc[4] = {0.f, 0.f, 0.f, 0.f};
  for (int k = 0; k < CIN; k++) {
    float w = ldf(W, (size_t)k * COUT + t, isf);
#pragma unroll
    for (int r = 0; r < 4; r++) acc[r] += at[r * CIN + k] * w;
  }
#pragma unroll
  for (int r = 0; r < 4; r++) C[(size_t)(n0 + r) * COUT + t] = acc[r];
}

// -------- hpre = B[4096,128] @ in_W[128,64]; 4 rows/block, wave->row --------
__global__ __launch_bounds__(256) void gemm_w64_kernel(
    const float* __restrict__ A, const void* __restrict__ W,
    const int* __restrict__ flagp, float* __restrict__ C) {
  int isf = *flagp;
  int t = threadIdx.x;
  int j = t & 63;
  int g = t >> 6;                              // wave id -> row g
  int n0 = blockIdx.x * 4;
  __shared__ float at[4 * CIN];                // 2 KB
  if (t < 128) ((float4*)at)[t] = ((const float4*)(A + (size_t)n0 * CIN))[t];
  __syncthreads();
  float a0 = 0.f;
  for (int k = 0; k < CIN; k++) a0 += at[g * CIN + k] * ldf(W, (size_t)k * WIDTH + j, isf);
  C[(size_t)(n0 + g) * WIDTH + j] = a0;
}

// -------- Y = lrelu(bn(X)) elementwise on ws f32, C channels pow2 --------
__global__ __launch_bounds__(256) void bnleaky_kernel(
    const float* __restrict__ X, const float* __restrict__ mean,
    const float* __restrict__ var,
    const void* __restrict__ g, const void* __restrict__ b,
    const int* __restrict__ flagp, float* __restrict__ Y, int Cmask) {
  int isf = *flagp;
  int idx = blockIdx.x * 256 + threadIdx.x;
  int c = idx & Cmask;
  float xn = (X[idx] - mean[c]) * rsqrtf(var[c] + BN_EPS);
  Y[idx] = lrelu(xn * ldf(g, c, isf) + ldf(b, c, isf), SLOPE);
}

// -------- fused convert of the 3 branch weight matrices -> f32 ws --------
__global__ __launch_bounds__(256) void cvt3_kernel(
    const void* __restrict__ W1, const void* __restrict__ W2,
    const void* __restrict__ W3, const int* __restrict__ flagp,
    float* __restrict__ dst) {   // dst = Wf1|Wf2|Wf3 contiguous (32K|16K|16K)
  int isf = *flagp;
  int i = blockIdx.x * 256 + threadIdx.x;   // 0..65535
  float v;
  if (i < 32768)      v = ldf(W1, i, isf);
  else if (i < 49152) v = ldf(W2, i - 32768, isf);
  else                v = ldf(W3, i - 49152, isf);
  dst[i] = v;
}

// -------- rowptr[b][n] = lower_bound(dst_b, n); rowptr[b][N] = E_b --------
__global__ __launch_bounds__(256) void rowptr_kernel(
    const int* __restrict__ d1, int E1, const int* __restrict__ d2, int E2,
    const int* __restrict__ d3, int E3, int* __restrict__ rp) {
  int t = blockIdx.x * 256 + threadIdx.x;   // 3 * (N+1)
  if (t >= 3 * (N_NODES + 1)) return;
  int b = t / (N_NODES + 1);
  int n = t % (N_NODES + 1);
  const int* d = (b == 0) ? d1 : (b == 1) ? d2 : d3;
  int E = (b == 0) ? E1 : (b == 1) ? E2 : E3;
  int lo = 0, hi = E;
  if (n >= N_NODES) lo = E;
  else {
    while (lo < hi) { int mid = (lo + hi) >> 1; if (d[mid] < n) lo = mid + 1; else hi = mid; }
  }
  rp[(size_t)b * (N_NODES + 1) + n] = lo;
}

// -------- fused per-edge gate weights for all 3 branches --------
struct EdgeParams {
  const int* src; const int* dst;
  const void* Ws; const void* bs;
  float* wbuf; int E; float inv_r; int hl;
};

#define WS_LD 113   // per-bin stride (7*16 + 1) -> spreads bins across banks
#define BS_LD 17

__global__ __launch_bounds__(256) void edge_w3_kernel(
    EdgeParams p0, EdgeParams p1, EdgeParams p2,
    const void* __restrict__ pos, const void* __restrict__ ori,
    const int* __restrict__ seq, const int* __restrict__ flagp) {
  int b = blockIdx.y;
  EdgeParams p = (b == 0) ? p0 : (b == 1) ? p1 : p2;
  int isf = *flagp;
  __shared__ float wsl[11 * WS_LD];
  __shared__ float bsl[11 * BS_LD];
  int L = 2 * p.hl + 1;
  for (int i = threadIdx.x; i < L * 112; i += 256) {
    int bin = i / 112, r = i - bin * 112;
    wsl[bin * WS_LD + r] = ldf(p.Ws, (size_t)bin * 112 + r, isf);
  }
  for (int i = threadIdx.x; i < L * 16; i += 256) {
    int bin = i >> 4, r = i & 15;
    bsl[bin * BS_LD + r] = ldf(p.bs, (size_t)bin * 16 + r, isf);
  }
  __syncthreads();
  int e = blockIdx.x * 256 + threadIdx.x;
  if (e >= p.E) return;
  int j = p.src[e], i = p.dst[e];
  float fi[9], fj[9];
  float px, py, pz;
  if (isf) {
    const float* orf = (const float*)ori;
    float4u a0 = *(const float4u*)(orf + (size_t)i * 9);
    float4u a1 = *(const float4u*)(orf + (size_t)i * 9 + 4);
    fi[0] = a0.x; fi[1] = a0.y; fi[2] = a0.z; fi[3] = a0.w;
    fi[4] = a1.x; fi[5] = a1.y; fi[6] = a1.z; fi[7] = a1.w;
    fi[8] = orf[(size_t)i * 9 + 8];
    float4u b0 = *(const float4u*)(orf + (size_t)j * 9);
    float4u b1 = *(const float4u*)(orf + (size_t)j * 9 + 4);
    fj[0] = b0.x; fj[1] = b0.y; fj[2] = b0.z; fj[3] = b0.w;
    fj[4] = b1.x; fj[5] = b1.y; fj[6] = b1.z; fj[7] = b1.w;
    fj[8] = orf[(size_t)j * 9 + 8];
    const float* pf = (const float*)pos;
    px = pf[j * 3 + 0] - pf[i * 3 + 0];
    py = pf[j * 3 + 1] - pf[i * 3 + 1];
    pz = pf[j * 3 + 2] - pf[i * 3 + 2];
  } else {
#pragma unroll
    for (int t = 0; t < 9; t++) {
      fi[t] = ldf(ori, (size_t)i * 9 + t, 0);
      fj[t] = ldf(ori, (size_t)j * 9 + t, 0);
    }
    px = ldf(pos, j * 3 + 0, 0) - ldf(pos, i * 3 + 0, 0);
    py = ldf(pos, j * 3 + 1, 0) - ldf(pos, i * 3 + 1, 0);
    pz = ldf(pos, j * 3 + 2, 0) - ldf(pos, i * 3 + 2, 0);
  }
  float dist = sqrtf(px * px + py * py + pz * pz);
  float inv = 1.0f / (dist + 1e-9f);
  float dx = px * inv, dy = py * inv, dz = pz * inv;
  float feat[7];
  feat[0] = dist * p.inv_r;
  feat[1] = fi[0] * dx + fi[1] * dy + fi[2] * dz;
  feat[2] = fi[3] * dx + fi[4] * dy + fi[5] * dz;
  feat[3] = fi[6] * dx + fi[7] * dy + fi[8] * dz;
  feat[4] = fi[0] * fj[0] + fi[1] * fj[1] + fi[2] * fj[2];
  feat[5] = fi[3] * fj[3] + fi[4] * fj[4] + fi[5] * fj[5];
  feat[6] = fi[6] * fj[6] + fi[7] * fj[7] + fi[8] * fj[8];
  int d = seq[j] - seq[i];
  d = d < -p.hl ? -p.hl : (d > p.hl ? p.hl : d);
  int bin = d + p.hl;
  const float* Wp = wsl + bin * WS_LD;
  const float* bp = bsl + bin * BS_LD;
  float w16[KDIM];
#pragma unroll
  for (int k = 0; k < KDIM; k++) {
    float a = bp[k];
#pragma unroll
    for (int c = 0; c < 7; c++) a += feat[c] * Wp[c * KDIM + k];
    w16[k] = lrelu(a, WSLOPE);
  }
  float4* wb = (float4*)(p.wbuf + (size_t)e * KDIM);
#pragma unroll
  for (int k = 0; k < 4; k++)
    wb[k] = make_float4(w16[4 * k], w16[4 * k + 1], w16[4 * k + 2], w16[4 * k + 3]);
}

// -------- fused per-node aggregation + branch GEMM, all 3 branches --------
// Block = 1 node (round-4 shape); 4 waves split edges stride-4, unroll x4 for
// 4 gathers in flight. LDS strips padded to 68-float k-rows so epilogue
// q-groups hit distinct banks.
struct AggParams {
  const int* src; const float* wbuf; const float* Wf;
  int O; int coloff;
};

#define ALD 68   // padded k-row stride (64 + 4)

__global__ __launch_bounds__(256) void agg3_kernel(
    AggParams p0, AggParams p1, AggParams p2,
    const int* __restrict__ rowptr,
    const float* __restrict__ h, float* __restrict__ cat) {
  int b = blockIdx.y;
  AggParams p = (b == 0) ? p0 : (b == 1) ? p1 : p2;
  int n = blockIdx.x;
  int t = threadIdx.x;
  int lane = t & 63;
  int wv = t >> 6;

  __shared__ float lds[4][KDIM * ALD];   // 4 x 1088 floats = 17408 B
  __shared__ float pw[4][WIDTH];

  const int* rp = rowptr + (size_t)b * (N_NODES + 1);
  int start = rp[n], end = rp[n + 1];

  float acc[KDIM];
#pragma unroll
  for (int k = 0; k < KDIM; k++) acc[k] = 0.f;

  int e = start + wv;
  // 4 edges in flight per wave
  for (; e + 12 < end; e += 16) {
    int j0 = p.src[e], j1 = p.src[e + 4], j2 = p.src[e + 8], j3 = p.src[e + 12];
    float hj0 = h[(size_t)j0 * WIDTH + lane];
    float hj1 = h[(size_t)j1 * WIDTH + lane];
    float hj2 = h[(size_t)j2 * WIDTH + lane];
    float hj3 = h[(size_t)j3 * WIDTH + lane];
    const float4* a0 = (const float4*)(p.wbuf + (size_t)e * KDIM);
    const float4* a1 = (const float4*)(p.wbuf + (size_t)(e + 4) * KDIM);
    const float4* a2 = (const float4*)(p.wbuf + (size_t)(e + 8) * KDIM);
    const float4* a3 = (const float4*)(p.wbuf + (size_t)(e + 12) * KDIM);
    float4 w00 = a0[0], w01 = a0[1], w02 = a0[2], w03 = a0[3];
    float4 w10 = a1[0], w11 = a1[1], w12 = a1[2], w13 = a1[3];
    float4 w20 = a2[0], w21 = a2[1], w22 = a2[2], w23 = a2[3];
    float4 w30 = a3[0], w31 = a3[1], w32 = a3[2], w33 = a3[3];
    acc[0] += w00.x * hj0; acc[1] += w00.y * hj0; acc[2] += w00.z * hj0; acc[3] += w00.w * hj0;
    acc[4] += w01.x * hj0; acc[5] += w01.y * hj0; acc[6] += w01.z * hj0; acc[7] += w01.w * hj0;
    acc[8] += w02.x * hj0; acc[9] += w02.y * hj0; acc[10] += w02.z * hj0; acc[11] += w02.w * hj0;
    acc[12] += w03.x * hj0; acc[13] += w03.y * hj0; acc[14] += w03.z * hj0; acc[15] += w03.w * hj0;
    acc[0] += w10.x * hj1; acc[1] += w10.y * hj1; acc[2] += w10.z * hj1; acc[3] += w10.w * hj1;
    acc[4] += w11.x * hj1; acc[5] += w11.y * hj1; acc[6] += w11.z * hj1; acc[7] += w11.w * hj1;
    acc[8] += w12.x * hj1; acc[9] += w12.y * hj1; acc[10] += w12.z * hj1; acc[11] += w12.w * hj1;
    acc[12] += w13.x * hj1; acc[13] += w13.y * hj1; acc[14] += w13.z * hj1; acc[15] += w13.w * hj1;
    acc[0] += w20.x * hj2; acc[1] += w20.y * hj2; acc[2] += w20.z * hj2; acc[3] += w20.w * hj2;
    acc[4] += w21.x * hj2; acc[5] += w21.y * hj2; acc[6] += w21.z * hj2; acc[7] += w21.w * hj2;
    acc[8] += w22.x * hj2; acc[9] += w22.y * hj2; acc[10] += w22.z * hj2; acc[11] += w22.w * hj2;
    acc[12] += w23.x * hj2; acc[13] += w23.y * hj2; acc[14] += w23.z * hj2; acc[15] += w23.w * hj2;
    acc[0] += w30.x * hj3; acc[1] += w30.y * hj3; acc[2] += w30.z * hj3; acc[3] += w30.w * hj3;
    acc[4] += w31.x * hj3; acc[5] += w31.y * hj3; acc[6] += w31.z * hj3; acc[7] += w31.w * hj3;
    acc[8] += w32.x * hj3; acc[9] += w32.y * hj3; acc[10] += w32.z * hj3; acc[11] += w32.w * hj3;
    acc[12] += w33.x * hj3; acc[13] += w33.y * hj3; acc[14] += w33.z * hj3; acc[15] += w33.w * hj3;
  }
  for (; e < end; e += 4) {
    int j = p.src[e];
    float hj = h[(size_t)j * WIDTH + lane];
    const float4* w4 = (const float4*)(p.wbuf + (size_t)e * KDIM);
    float4 w0 = w4[0], w1 = w4[1], w2 = w4[2], w3 = w4[3];
    acc[0] += w0.x * hj; acc[1] += w0.y * hj; acc[2] += w0.z * hj; acc[3] += w0.w * hj;
    acc[4] += w1.x * hj; acc[5] += w1.y * hj; acc[6] += w1.z * hj; acc[7] += w1.w * hj;
    acc[8] += w2.x * hj; acc[9] += w2.y * hj; acc[10] += w2.z * hj; acc[11] += w2.w * hj;
    acc[12] += w3.x * hj; acc[13] += w3.y * hj; acc[14] += w3.z * hj; acc[15] += w3.w * hj;
  }

#pragma unroll
  for (int k = 0; k < KDIM; k++) lds[wv][k * ALD + lane] = acc[k];
  __syncthreads();

  // sum the 4 wave strips into strip 0 (pads carry garbage; never read)
  for (int i = t; i < KDIM * ALD; i += 256)
    lds[0][i] = lds[0][i] + lds[1][i] + lds[2][i] + lds[3][i];
  __syncthreads();

  // epilogue: out[o] = sum_{k,c} agg[k][c] * Wf[(k*64+c)*O + o]
  int O = p.O;
  int o = t & (O - 1);
  int q = t / O;
  int kpg = O >> 4;                      // k's per group: O=32 -> 2, O=16 -> 1
  float part = 0.f;
  for (int kk = 0; kk < kpg; kk++) {
    int k = q * kpg + kk;
    const float* ar = lds[0] + k * ALD;
    const float* wf = p.Wf + (size_t)(k * WIDTH) * O + o;
    for (int c = 0; c < WIDTH; c += 4) {
      float4 a = *(const float4*)(ar + c);
      part += a.x * wf[(size_t)(c + 0) * O];
      part += a.y * wf[(size_t)(c + 1) * O];
      part += a.z * wf[(size_t)(c + 2) * O];
      part += a.w * wf[(size_t)(c + 3) * O];
    }
  }
  for (int m = O; m < 64; m <<= 1) part += __shfl_xor(part, m, 64);
  if (lane < O) pw[wv][lane] = part;
  __syncthreads();
  if (t < O)
    cat[(size_t)n * WIDTH + p.coloff + t] = pw[0][t] + pw[1][t] + pw[2][t] + pw[3][t];
}

// -------- out = lrelu(bn(cat)) @ outW + identity; 8 nodes/block ------------
__global__ __launch_bounds__(256) void final_kernel(
    const float* __restrict__ cat, const float* __restrict__ mean,
    const float* __restrict__ var,
    const void* __restrict__ g, const void* __restrict__ b,
    const void* __restrict__ outW, const int* __restrict__ flagp,
    const float* __restrict__ identity, void* __restrict__ out) {
  int isf = *flagp;
  int t = threadIdx.x;   // 256 = COUT; one output column per thread
  int n0 = blockIdx.x * 8;
  __shared__ float cn8[8 * WIDTH];   // 2 KB
#pragma unroll
  for (int s = 0; s < 2; s++) {
    int ii = s * 256 + t;            // 0..511
    int r = ii >> 6, k = ii & 63;
    float xn = (cat[(size_t)(n0 + r) * WIDTH + k] - mean[k]) * rsqrtf(var[k] + BN_EPS);
    cn8[ii] = lrelu(xn * ldf(g, k, isf) + ldf(b, k, isf), SLOPE);
  }
  __syncthreads();
  float acc[8];
#pragma unroll
  for (int r = 0; r < 8; r++) acc[r] = identity[(size_t)(n0 + r) * COUT + t];
  for (int k = 0; k < WIDTH; k++) {
    float w = ldf(outW, (size_t)k * COUT + t, isf);
#pragma unroll
    for (int r = 0; r < 8; r++) acc[r] += cn8[r * WIDTH + k] * w;
  }
#pragma unroll
  for (int r = 0; r < 8; r++) {
    size_t oidx = (size_t)(n0 + r) * COUT + t;
    if (isf) ((float*)out)[oidx] = acc[r];
    else     ((__hip_bfloat16*)out)[oidx] = __float2bfloat16(acc[r]);
  }
}

extern "C" void kernel_launch(void* const* d_in, const int* in_sizes, int n_in,
                              void* d_out, int out_size, void* d_ws, size_t ws_size,
                              hipStream_t stream) {
  const void* x    = d_in[0];
  const void* pos  = d_in[1];
  const void* ori  = d_in[2];
  const int* seq  = (const int*)d_in[3];
  const int* src1 = (const int*)d_in[5];  const int* dst1 = (const int*)d_in[6];
  const int* src2 = (const int*)d_in[7];  const int* dst2 = (const int*)d_in[8];
  const int* src3 = (const int*)d_in[9];  const int* dst3 = (const int*)d_in[10];
  const void* id_g  = d_in[11]; const void* id_b  = d_in[12]; const void* id_W = d_in[13];
  const void* in_g  = d_in[14]; const void* in_b  = d_in[15]; const void* in_W = d_in[16];
  const void* mid_g = d_in[17]; const void* mid_b = d_in[18];
  const void* Ws1   = d_in[19]; const void* bs1   = d_in[20]; const void* W1   = d_in[21];
  const void* Ws2   = d_in[22]; const void* bs2   = d_in[23]; const void* W2   = d_in[24];
  const void* Ws3   = d_in[25]; const void* bs3   = d_in[26]; const void* W3   = d_in[27];
  const void* out_g = d_in[28]; const void* out_b = d_in[29]; const void* out_W = d_in[30];

  const int E1 = in_sizes[5], E2 = in_sizes[7], E3 = in_sizes[9];

  float* wsp = (float*)d_ws;
  size_t off = 0;
  auto alloc = [&](size_t n) { float* p = wsp + off; off += (n + 63) & ~(size_t)63; return p; };
  int*   flag  = (int*)alloc(64);
  float* meanx = alloc(CIN);   float* varx = alloc(CIN);
  float* meanh = alloc(WIDTH); float* varh = alloc(WIDTH);
  float* meanc = alloc(WIDTH); float* varc = alloc(WIDTH);
  float* A     = alloc((size_t)N_NODES * CIN);
  float* B     = alloc((size_t)N_NODES * CIN);
  float* ident = alloc((size_t)N_NODES * COUT);
  float* hpre  = alloc((size_t)N_NODES * WIDTH);
  float* hbuf  = alloc((size_t)N_NODES * WIDTH);
  float* catb  = alloc((size_t)N_NODES * WIDTH);
  float* Wf1   = alloc(1024 * 32);        // contiguous: Wf1|Wf2|Wf3
  float* Wf2   = alloc(1024 * 16);
  float* Wf3   = alloc(1024 * 16);
  int*   rowp  = (int*)alloc(3 * (N_NODES + 1));
  float* w1    = alloc((size_t)E1 * KDIM);
  float* w2    = alloc((size_t)E2 * KDIM);
  float* w3    = alloc((size_t)E3 * KDIM);
  (void)ws_size; (void)n_in; (void)out_size;

  // 0. dtype sniff
  sniff_kernel<<<1, 64, 0, stream>>>(x, flag);
  // 1. stats of x (shared by id/in BN)
  col_stats4_in_kernel<<<CIN / 4, 256, 0, stream>>>(x, flag, meanx, varx);
  // 2. A/B activations
  act_ab_kernel<<<(N_NODES * CIN) / 256, 256, 0, stream>>>(x, flag, meanx, varx, id_g, id_b, in_g, in_b, A, B);
  // 3. identity = A @ id_W ; h_pre = B @ in_W (4 rows/block)
  gemm_cout_kernel<<<N_NODES / 4, 256, 0, stream>>>(A, id_W, flag, ident);
  gemm_w64_kernel<<<N_NODES / 4, 256, 0, stream>>>(B, in_W, flag, hpre);
  // 4. mid BN stats + activation -> h
  col_stats4_f32_kernel<<<WIDTH / 4, 256, 0, stream>>>(hpre, WIDTH, meanh, varh);
  bnleaky_kernel<<<(N_NODES * WIDTH) / 256, 256, 0, stream>>>(hpre, meanh, varh, mid_g, mid_b, flag, hbuf, WIDTH - 1);
  // 5. branch GEMM weights -> f32 (fused), rowptr (fused)
  cvt3_kernel<<<65536 / 256, 256, 0, stream>>>(W1, W2, W3, flag, Wf1);
  rowptr_kernel<<<(3 * (N_NODES + 1) + 255) / 256, 256, 0, stream>>>(dst1, E1, dst2, E2, dst3, E3, rowp);
  // 6. per-edge gate weights (fused over branches, LDS-staged Ws/bs)
  EdgeParams ep0{src1, dst1, Ws1, bs1, w1, E1, 1.0f / 2.70f, 2};
  EdgeParams ep1{src2, dst2, Ws2, bs2, w2, E2, 1.0f / 1.80f, 3};
  EdgeParams ep2{src3, dst3, Ws3, bs3, w3, E3, 1.0f / 1.35f, 5};
  int maxE = E1 > E2 ? (E1 > E3 ? E1 : E3) : (E2 > E3 ? E2 : E3);
  edge_w3_kernel<<<dim3((maxE + 255) / 256, 3), 256, 0, stream>>>(ep0, ep1, ep2, pos, ori, seq, flag);
  // 7. fused per-node aggregation + branch GEMMs -> cat (1 node/block)
  AggParams ap0{src1, w1, Wf1, 32, 0};
  AggParams ap1{src2, w2, Wf2, 16, 32};
  AggParams ap2{src3, w3, Wf3, 16, 48};
  agg3_kernel<<<dim3(N_NODES, 3), 256, 0, stream>>>(ap0, ap1, ap2, rowp, hbuf, catb);
  // 8. out BN stats + final GEMM + residual (8 nodes/block)
  col_stats4_f32_kernel<<<WIDTH / 4, 256, 0, stream>>>(catb, WIDTH, meanc, varc);
  final_kernel<<<N_NODES / 8, 256, 0, stream>>>(catb, meanc, varc, out_g, out_b, out_W, flag, ident, d_out);
}

// Round 7
// 233.912 us; speedup vs baseline: 1.4277x; 1.1590x over previous
//
#include <hip/hip_runtime.h>

#define N_NODES 4096
#define CIN     128
#define COUT    256
#define WIDTH   64
#define KDIM    16
#define SLOPE   0.1f
#define WSLOPE  0.2f
#define BN_EPS  1e-5f

typedef float float4u __attribute__((ext_vector_type(4), aligned(4)));

__device__ __forceinline__ float lrelu(float x, float s) { return x > 0.f ? x : s * x; }

// ======================= prep: stats_x + rowptr + edge_w =====================
// blocks [0,32): column stats of x -> (sA,hA) id-affine, (sB,hB) in-affine
// blocks [32,81): rowptr binary searches (3*(N+1) entries)
// blocks [81,...): per-edge gate weights, branch by block range
struct EdgeP {
  const int* src; const int* dst;
  const float* Ws; const float* bs;
  float* wbuf; int E; float inv_r; int hl;
};

#define WS_LD 113
#define BS_LD 17
#define NB_STATSX 32
#define NB_ROWPTR 49

__global__ __launch_bounds__(256) void prep_kernel(
    const float* __restrict__ x,
    const float* __restrict__ id_g, const float* __restrict__ id_b,
    const float* __restrict__ in_g, const float* __restrict__ in_b,
    float* __restrict__ sA, float* __restrict__ hA,
    float* __restrict__ sB, float* __restrict__ hB,
    int* __restrict__ rowp,
    EdgeP e0, EdgeP e1, EdgeP e2,
    const float* __restrict__ pos, const float* __restrict__ ori,
    const int* __restrict__ seq,
    int nb1, int nb2)
{
  int bx = blockIdx.x, t = threadIdx.x;

  if (bx < NB_STATSX) {
    // ---- column stats of x (4 channels per block) + both affines ----
    int cg = bx;
    int lane = t & 63, wv = t >> 6;
    float s[4] = {0.f, 0.f, 0.f, 0.f}, q[4] = {0.f, 0.f, 0.f, 0.f};
    for (int r = t; r < N_NODES; r += 256) {
      float4u a = *(const float4u*)(x + (size_t)r * CIN + cg * 4);
      float v[4] = {a.x, a.y, a.z, a.w};
#pragma unroll
      for (int i = 0; i < 4; i++) { s[i] += v[i]; q[i] += v[i] * v[i]; }
    }
#pragma unroll
    for (int m = 1; m < 64; m <<= 1) {
#pragma unroll
      for (int i = 0; i < 4; i++) { s[i] += __shfl_xor(s[i], m, 64); q[i] += __shfl_xor(q[i], m, 64); }
    }
    __shared__ float rs[4][4], rq[4][4];
    if (lane == 0) {
#pragma unroll
      for (int i = 0; i < 4; i++) { rs[wv][i] = s[i]; rq[wv][i] = q[i]; }
    }
    __syncthreads();
    if (t < 4) {
      float S = rs[0][t] + rs[1][t] + rs[2][t] + rs[3][t];
      float Q = rq[0][t] + rq[1][t] + rq[2][t] + rq[3][t];
      float m = S / N_NODES;
      float v = Q / N_NODES - m * m;
      float rsv = rsqrtf(v + BN_EPS);
      int c = cg * 4 + t;
      float sa = id_g[c] * rsv;
      float sb = in_g[c] * rsv;
      sA[c] = sa; hA[c] = id_b[c] - m * sa;
      sB[c] = sb; hB[c] = in_b[c] - m * sb;
    }
    return;
  }

  if (bx < NB_STATSX + NB_ROWPTR) {
    // ---- rowptr: lower_bound(dst_b, n) for all (b, n) ----
    int idx = (bx - NB_STATSX) * 256 + t;
    if (idx >= 3 * (N_NODES + 1)) return;
    int b = idx / (N_NODES + 1);
    int n = idx % (N_NODES + 1);
    const int* d = (b == 0) ? e0.dst : (b == 1) ? e1.dst : e2.dst;
    int E = (b == 0) ? e0.E : (b == 1) ? e1.E : e2.E;
    int lo = 0, hi = E;
    if (n >= N_NODES) lo = E;
    else {
      while (lo < hi) { int mid = (lo + hi) >> 1; if (d[mid] < n) lo = mid + 1; else hi = mid; }
    }
    rowp[(size_t)b * (N_NODES + 1) + n] = lo;
    return;
  }

  // ---- per-edge gate weights ----
  int eb = bx - (NB_STATSX + NB_ROWPTR);
  EdgeP p;
  int base;
  if (eb < nb1)            { p = e0; base = eb; }
  else if (eb < nb1 + nb2) { p = e1; base = eb - nb1; }
  else                     { p = e2; base = eb - nb1 - nb2; }

  __shared__ float wsl[11 * WS_LD];
  __shared__ float bsl[11 * BS_LD];
  int L = 2 * p.hl + 1;
  for (int i = t; i < L * 112; i += 256) {
    int bin = i / 112, r = i - bin * 112;
    wsl[bin * WS_LD + r] = p.Ws[(size_t)bin * 112 + r];
  }
  for (int i = t; i < L * 16; i += 256) {
    int bin = i >> 4, r = i & 15;
    bsl[bin * BS_LD + r] = p.bs[(size_t)bin * 16 + r];
  }
  __syncthreads();

  int e = base * 256 + t;
  if (e >= p.E) return;
  int j = p.src[e], i = p.dst[e];
  float px = pos[j * 3 + 0] - pos[i * 3 + 0];
  float py = pos[j * 3 + 1] - pos[i * 3 + 1];
  float pz = pos[j * 3 + 2] - pos[i * 3 + 2];
  float fi[9], fj[9];
  {
    float4u a0 = *(const float4u*)(ori + (size_t)i * 9);
    float4u a1 = *(const float4u*)(ori + (size_t)i * 9 + 4);
    fi[0] = a0.x; fi[1] = a0.y; fi[2] = a0.z; fi[3] = a0.w;
    fi[4] = a1.x; fi[5] = a1.y; fi[6] = a1.z; fi[7] = a1.w;
    fi[8] = ori[(size_t)i * 9 + 8];
    float4u b0 = *(const float4u*)(ori + (size_t)j * 9);
    float4u b1 = *(const float4u*)(ori + (size_t)j * 9 + 4);
    fj[0] = b0.x; fj[1] = b0.y; fj[2] = b0.z; fj[3] = b0.w;
    fj[4] = b1.x; fj[5] = b1.y; fj[6] = b1.z; fj[7] = b1.w;
    fj[8] = ori[(size_t)j * 9 + 8];
  }
  float dist = sqrtf(px * px + py * py + pz * pz);
  float inv = 1.0f / (dist + 1e-9f);
  float dx = px * inv, dy = py * inv, dz = pz * inv;
  float feat[7];
  feat[0] = dist * p.inv_r;
  feat[1] = fi[0] * dx + fi[1] * dy + fi[2] * dz;
  feat[2] = fi[3] * dx + fi[4] * dy + fi[5] * dz;
  feat[3] = fi[6] * dx + fi[7] * dy + fi[8] * dz;
  feat[4] = fi[0] * fj[0] + fi[1] * fj[1] + fi[2] * fj[2];
  feat[5] = fi[3] * fj[3] + fi[4] * fj[4] + fi[5] * fj[5];
  feat[6] = fi[6] * fj[6] + fi[7] * fj[7] + fi[8] * fj[8];
  int d = seq[j] - seq[i];
  d = d < -p.hl ? -p.hl : (d > p.hl ? p.hl : d);
  int bin = d + p.hl;
  const float* Wp = wsl + bin * WS_LD;
  const float* bp = bsl + bin * BS_LD;
  float w16[KDIM];
#pragma unroll
  for (int k = 0; k < KDIM; k++) {
    float a = bp[k];
#pragma unroll
    for (int c = 0; c < 7; c++) a += feat[c] * Wp[c * KDIM + k];
    w16[k] = lrelu(a, WSLOPE);
  }
  float4* wb = (float4*)(p.wbuf + (size_t)e * KDIM);
#pragma unroll
  for (int k = 0; k < 4; k++)
    wb[k] = make_float4(w16[4 * k], w16[4 * k + 1], w16[4 * k + 2], w16[4 * k + 3]);
}

// =========== gemm2: ident = act_id(x)@id_W  |  hpre = act_in(x)@in_W ========
// blocks [0,512): cout path (8 rows, thread=col). blocks [512,1024): w64 path.
__global__ __launch_bounds__(256) void gemm2_kernel(
    const float* __restrict__ x,
    const float* __restrict__ sA, const float* __restrict__ hA,
    const float* __restrict__ sB, const float* __restrict__ hB,
    const float* __restrict__ idW, const float* __restrict__ inW,
    float* __restrict__ ident, float* __restrict__ hpre)
{
  int bx = blockIdx.x, t = threadIdx.x;
  __shared__ float at[8 * CIN];   // 4 KB, bn+lrelu applied
  bool coutp = bx < 512;
  int n0 = (coutp ? bx : bx - 512) * 8;
  {
    int r = t >> 5, c4 = (t & 31) * 4;
    const float* S = coutp ? sA : sB;
    const float* H = coutp ? hA : hB;
    float4u xv = *(const float4u*)(x + (size_t)(n0 + r) * CIN + c4);
    float4u sv = *(const float4u*)(S + c4);
    float4u hv = *(const float4u*)(H + c4);
    float4u o;
    o.x = lrelu(xv.x * sv.x + hv.x, SLOPE);
    o.y = lrelu(xv.y * sv.y + hv.y, SLOPE);
    o.z = lrelu(xv.z * sv.z + hv.z, SLOPE);
    o.w = lrelu(xv.w * sv.w + hv.w, SLOPE);
    *(float4u*)(at + r * CIN + c4) = o;
  }
  __syncthreads();
  if (coutp) {
    float acc[8] = {0.f, 0.f, 0.f, 0.f, 0.f, 0.f, 0.f, 0.f};
    for (int k = 0; k < CIN; k += 4) {
      float w0 = idW[(size_t)(k + 0) * COUT + t];
      float w1 = idW[(size_t)(k + 1) * COUT + t];
      float w2 = idW[(size_t)(k + 2) * COUT + t];
      float w3 = idW[(size_t)(k + 3) * COUT + t];
#pragma unroll
      for (int r8 = 0; r8 < 8; r8++) {
        float4u a = *(const float4u*)(at + r8 * CIN + k);
        acc[r8] += a.x * w0 + a.y * w1 + a.z * w2 + a.w * w3;
      }
    }
#pragma unroll
    for (int r8 = 0; r8 < 8; r8++) ident[(size_t)(n0 + r8) * COUT + t] = acc[r8];
  } else {
    int j = t & 63, g = t >> 6;
    float a0 = 0.f, a1 = 0.f;
    for (int k = 0; k < CIN; k += 4) {
      float w0 = inW[(size_t)(k + 0) * WIDTH + j];
      float w1 = inW[(size_t)(k + 1) * WIDTH + j];
      float w2 = inW[(size_t)(k + 2) * WIDTH + j];
      float w3 = inW[(size_t)(k + 3) * WIDTH + j];
      float4u u = *(const float4u*)(at + (2 * g) * CIN + k);
      float4u v = *(const float4u*)(at + (2 * g + 1) * CIN + k);
      a0 += u.x * w0 + u.y * w1 + u.z * w2 + u.w * w3;
      a1 += v.x * w0 + v.y * w1 + v.z * w2 + v.w * w3;
    }
    hpre[(size_t)(n0 + 2 * g) * WIDTH + j] = a0;
    hpre[(size_t)(n0 + 2 * g + 1) * WIDTH + j] = a1;
  }
}

// ====== stats_affine: col stats of X[4096,C] -> s = g*rsqrt(v+eps), h = b-m*s
__global__ __launch_bounds__(256) void stats_affine_kernel(
    const float* __restrict__ X, int C,
    const float* __restrict__ g, const float* __restrict__ b,
    float* __restrict__ s_out, float* __restrict__ h_out)
{
  int cg = blockIdx.x;
  int t = threadIdx.x, lane = t & 63, wv = t >> 6;
  float s[4] = {0.f, 0.f, 0.f, 0.f}, q[4] = {0.f, 0.f, 0.f, 0.f};
  for (int r = t; r < N_NODES; r += 256) {
    float4u a = *(const float4u*)(X + (size_t)r * C + cg * 4);
    float v[4] = {a.x, a.y, a.z, a.w};
#pragma unroll
    for (int i = 0; i < 4; i++) { s[i] += v[i]; q[i] += v[i] * v[i]; }
  }
#pragma unroll
  for (int m = 1; m < 64; m <<= 1) {
#pragma unroll
    for (int i = 0; i < 4; i++) { s[i] += __shfl_xor(s[i], m, 64); q[i] += __shfl_xor(q[i], m, 64); }
  }
  __shared__ float rs[4][4], rq[4][4];
  if (lane == 0) {
#pragma unroll
    for (int i = 0; i < 4; i++) { rs[wv][i] = s[i]; rq[wv][i] = q[i]; }
  }
  __syncthreads();
  if (t < 4) {
    float S = rs[0][t] + rs[1][t] + rs[2][t] + rs[3][t];
    float Q = rq[0][t] + rq[1][t] + rq[2][t] + rq[3][t];
    float m = S / N_NODES;
    float v = Q / N_NODES - m * m;
    int c = cg * 4 + t;
    float sv = g[c] * rsqrtf(v + BN_EPS);
    s_out[c] = sv;
    h_out[c] = b[c] - m * sv;
  }
}

// ============== agg3: per-node aggregation + branch GEMM (fused BN) =========
struct AggP {
  const int* src; const float* wbuf; const float* Wf;
  int O; int coloff;
};

#define ALD 68   // padded k-row stride

__global__ __launch_bounds__(256) void agg3_kernel(
    AggP p0, AggP p1, AggP p2, const int* __restrict__ rowp,
    const float* __restrict__ hpre,
    const float* __restrict__ sH, const float* __restrict__ hH,
    float* __restrict__ cat)
{
  int b = blockIdx.y;
  AggP p = (b == 0) ? p0 : (b == 1) ? p1 : p2;
  int n = blockIdx.x, t = threadIdx.x, lane = t & 63, wv = t >> 6;

  __shared__ float lds[4][KDIM * ALD];
  __shared__ float pw[4][WIDTH];

  float scH = sH[lane], shH = hH[lane];
  const int* rp = rowp + (size_t)b * (N_NODES + 1);
  int start = rp[n], end = rp[n + 1];

  float acc[KDIM];
#pragma unroll
  for (int k = 0; k < KDIM; k++) acc[k] = 0.f;

  int e = start + wv;
  for (; e + 12 < end; e += 16) {
    int j0 = __builtin_amdgcn_readfirstlane(p.src[e]);
    int j1 = __builtin_amdgcn_readfirstlane(p.src[e + 4]);
    int j2 = __builtin_amdgcn_readfirstlane(p.src[e + 8]);
    int j3 = __builtin_amdgcn_readfirstlane(p.src[e + 12]);
    float r0 = hpre[(size_t)j0 * WIDTH + lane];
    float r1 = hpre[(size_t)j1 * WIDTH + lane];
    float r2 = hpre[(size_t)j2 * WIDTH + lane];
    float r3 = hpre[(size_t)j3 * WIDTH + lane];
    const float4* a0 = (const float4*)(p.wbuf + (size_t)e * KDIM);
    const float4* a1 = (const float4*)(p.wbuf + (size_t)(e + 4) * KDIM);
    const float4* a2 = (const float4*)(p.wbuf + (size_t)(e + 8) * KDIM);
    const float4* a3 = (const float4*)(p.wbuf + (size_t)(e + 12) * KDIM);
    float4 w00 = a0[0], w01 = a0[1], w02 = a0[2], w03 = a0[3];
    float4 w10 = a1[0], w11 = a1[1], w12 = a1[2], w13 = a1[3];
    float4 w20 = a2[0], w21 = a2[1], w22 = a2[2], w23 = a2[3];
    float4 w30 = a3[0], w31 = a3[1], w32 = a3[2], w33 = a3[3];
    float hj0 = lrelu(r0 * scH + shH, SLOPE);
    float hj1 = lrelu(r1 * scH + shH, SLOPE);
    float hj2 = lrelu(r2 * scH + shH, SLOPE);
    float hj3 = lrelu(r3 * scH + shH, SLOPE);
    acc[0] += w00.x * hj0; acc[1] += w00.y * hj0; acc[2] += w00.z * hj0; acc[3] += w00.w * hj0;
    acc[4] += w01.x * hj0; acc[5] += w01.y * hj0; acc[6] += w01.z * hj0; acc[7] += w01.w * hj0;
    acc[8] += w02.x * hj0; acc[9] += w02.y * hj0; acc[10] += w02.z * hj0; acc[11] += w02.w * hj0;
    acc[12] += w03.x * hj0; acc[13] += w03.y * hj0; acc[14] += w03.z * hj0; acc[15] += w03.w * hj0;
    acc[0] += w10.x * hj1; acc[1] += w10.y * hj1; acc[2] += w10.z * hj1; acc[3] += w10.w * hj1;
    acc[4] += w11.x * hj1; acc[5] += w11.y * hj1; acc[6] += w11.z * hj1; acc[7] += w11.w * hj1;
    acc[8] += w12.x * hj1; acc[9] += w12.y * hj1; acc[10] += w12.z * hj1; acc[11] += w12.w * hj1;
    acc[12] += w13.x * hj1; acc[13] += w13.y * hj1; acc[14] += w13.z * hj1; acc[15] += w13.w * hj1;
    acc[0] += w20.x * hj2; acc[1] += w20.y * hj2; acc[2] += w20.z * hj2; acc[3] += w20.w * hj2;
    acc[4] += w21.x * hj2; acc[5] += w21.y * hj2; acc[6] += w21.z * hj2; acc[7] += w21.w * hj2;
    acc[8] += w22.x * hj2; acc[9] += w22.y * hj2; acc[10] += w22.z * hj2; acc[11] += w22.w * hj2;
    acc[12] += w23.x * hj2; acc[13] += w23.y * hj2; acc[14] += w23.z * hj2; acc[15] += w23.w * hj2;
    acc[0] += w30.x * hj3; acc[1] += w30.y * hj3; acc[2] += w30.z * hj3; acc[3] += w30.w * hj3;
    acc[4] += w31.x * hj3; acc[5] += w31.y * hj3; acc[6] += w31.z * hj3; acc[7] += w31.w * hj3;
    acc[8] += w32.x * hj3; acc[9] += w32.y * hj3; acc[10] += w32.z * hj3; acc[11] += w32.w * hj3;
    acc[12] += w33.x * hj3; acc[13] += w33.y * hj3; acc[14] += w33.z * hj3; acc[15] += w33.w * hj3;
  }
  for (; e < end; e += 4) {
    int j = __builtin_amdgcn_readfirstlane(p.src[e]);
    float hr = hpre[(size_t)j * WIDTH + lane];
    const float4* w4 = (const float4*)(p.wbuf + (size_t)e * KDIM);
    float4 w0 = w4[0], w1 = w4[1], w2 = w4[2], w3 = w4[3];
    float hj = lrelu(hr * scH + shH, SLOPE);
    acc[0] += w0.x * hj; acc[1] += w0.y * hj; acc[2] += w0.z * hj; acc[3] += w0.w * hj;
    acc[4] += w1.x * hj; acc[5] += w1.y * hj; acc[6] += w1.z * hj; acc[7] += w1.w * hj;
    acc[8] += w2.x * hj; acc[9] += w2.y * hj; acc[10] += w2.z * hj; acc[11] += w2.w * hj;
    acc[12] += w3.x * hj; acc[13] += w3.y * hj; acc[14] += w3.z * hj; acc[15] += w3.w * hj;
  }

#pragma unroll
  for (int k = 0; k < KDIM; k++) lds[wv][k * ALD + lane] = acc[k];
  __syncthreads();

  for (int i = t; i < KDIM * ALD; i += 256)
    lds[0][i] = lds[0][i] + lds[1][i] + lds[2][i] + lds[3][i];
  __syncthreads();

  int O = p.O;
  int o = t & (O - 1);
  int q = t / O;
  int kpg = O >> 4;
  float part = 0.f;
  for (int kk = 0; kk < kpg; kk++) {
    int k = q * kpg + kk;
    const float* ar = lds[0] + k * ALD;
    const float* wf = p.Wf + (size_t)(k * WIDTH) * O + o;
    for (int c = 0; c < WIDTH; c += 4) {
      float4 a = *(const float4*)(ar + c);
      part += a.x * wf[(size_t)(c + 0) * O];
      part += a.y * wf[(size_t)(c + 1) * O];
      part += a.z * wf[(size_t)(c + 2) * O];
      part += a.w * wf[(size_t)(c + 3) * O];
    }
  }
  for (int m = O; m < 64; m <<= 1) part += __shfl_xor(part, m, 64);
  if (lane < O) pw[wv][lane] = part;
  __syncthreads();
  if (t < O)
    cat[(size_t)n * WIDTH + p.coloff + t] = pw[0][t] + pw[1][t] + pw[2][t] + pw[3][t];
}

// ============ final: out = lrelu(bn(cat))@outW + ident; 8 nodes/block =======
__global__ __launch_bounds__(256) void final_kernel(
    const float* __restrict__ cat,
    const float* __restrict__ sC, const float* __restrict__ hC,
    const float* __restrict__ outW,
    const float* __restrict__ identity, float* __restrict__ out)
{
  int t = threadIdx.x;
  int n0 = blockIdx.x * 8;
  __shared__ float cn8[8 * WIDTH];
#pragma unroll
  for (int s = 0; s < 2; s++) {
    int ii = s * 256 + t;
    int r = ii >> 6, k = ii & 63;
    cn8[ii] = lrelu(cat[(size_t)(n0 + r) * WIDTH + k] * sC[k] + hC[k], SLOPE);
  }
  __syncthreads();
  float acc[8];
#pragma unroll
  for (int r = 0; r < 8; r++) acc[r] = identity[(size_t)(n0 + r) * COUT + t];
  for (int k = 0; k < WIDTH; k += 4) {
    float w0 = outW[(size_t)(k + 0) * COUT + t];
    float w1 = outW[(size_t)(k + 1) * COUT + t];
    float w2 = outW[(size_t)(k + 2) * COUT + t];
    float w3 = outW[(size_t)(k + 3) * COUT + t];
#pragma unroll
    for (int r = 0; r < 8; r++) {
      float4u a = *(const float4u*)(cn8 + r * WIDTH + k);
      acc[r] += a.x * w0 + a.y * w1 + a.z * w2 + a.w * w3;
    }
  }
#pragma unroll
  for (int r = 0; r < 8; r++) out[(size_t)(n0 + r) * COUT + t] = acc[r];
}

extern "C" void kernel_launch(void* const* d_in, const int* in_sizes, int n_in,
                              void* d_out, int out_size, void* d_ws, size_t ws_size,
                              hipStream_t stream) {
  const float* x    = (const float*)d_in[0];
  const float* pos  = (const float*)d_in[1];
  const float* ori  = (const float*)d_in[2];
  const int* seq  = (const int*)d_in[3];
  const int* src1 = (const int*)d_in[5];  const int* dst1 = (const int*)d_in[6];
  const int* src2 = (const int*)d_in[7];  const int* dst2 = (const int*)d_in[8];
  const int* src3 = (const int*)d_in[9];  const int* dst3 = (const int*)d_in[10];
  const float* id_g  = (const float*)d_in[11]; const float* id_b  = (const float*)d_in[12];
  const float* id_W  = (const float*)d_in[13];
  const float* in_g  = (const float*)d_in[14]; const float* in_b  = (const float*)d_in[15];
  const float* in_W  = (const float*)d_in[16];
  const float* mid_g = (const float*)d_in[17]; const float* mid_b = (const float*)d_in[18];
  const float* Ws1   = (const float*)d_in[19]; const float* bs1   = (const float*)d_in[20];
  const float* W1    = (const float*)d_in[21];
  const float* Ws2   = (const float*)d_in[22]; const float* bs2   = (const float*)d_in[23];
  const float* W2    = (const float*)d_in[24];
  const float* Ws3   = (const float*)d_in[25]; const float* bs3   = (const float*)d_in[26];
  const float* W3    = (const float*)d_in[27];
  const float* out_g = (const float*)d_in[28]; const float* out_b = (const float*)d_in[29];
  const float* out_W = (const float*)d_in[30];

  const int E1 = in_sizes[5], E2 = in_sizes[7], E3 = in_sizes[9];

  float* wsp = (float*)d_ws;
  size_t off = 0;
  auto alloc = [&](size_t n) { float* p = wsp + off; off += (n + 63) & ~(size_t)63; return p; };
  float* sA   = alloc(CIN);   float* hA = alloc(CIN);
  float* sB   = alloc(CIN);   float* hB = alloc(CIN);
  float* sH   = alloc(WIDTH); float* hH = alloc(WIDTH);
  float* sC   = alloc(WIDTH); float* hC = alloc(WIDTH);
  float* ident = alloc((size_t)N_NODES * COUT);
  float* hpre  = alloc((size_t)N_NODES * WIDTH);
  float* catb  = alloc((size_t)N_NODES * WIDTH);
  int*   rowp  = (int*)alloc(3 * (N_NODES + 1));
  float* w1    = alloc((size_t)E1 * KDIM);
  float* w2    = alloc((size_t)E2 * KDIM);
  float* w3    = alloc((size_t)E3 * KDIM);
  (void)ws_size; (void)n_in; (void)out_size;

  int nb1 = (E1 + 255) / 256, nb2 = (E2 + 255) / 256, nb3 = (E3 + 255) / 256;

  EdgeP e0{src1, dst1, Ws1, bs1, w1, E1, 1.0f / 2.70f, 2};
  EdgeP e1{src2, dst2, Ws2, bs2, w2, E2, 1.0f / 1.80f, 3};
  EdgeP e2{src3, dst3, Ws3, bs3, w3, E3, 1.0f / 1.35f, 5};

  // 1. prep: x-stats(+affines) | rowptr | edge gate weights
  prep_kernel<<<NB_STATSX + NB_ROWPTR + nb1 + nb2 + nb3, 256, 0, stream>>>(
      x, id_g, id_b, in_g, in_b, sA, hA, sB, hB, rowp,
      e0, e1, e2, pos, ori, seq, nb1, nb2);
  // 2. both input GEMMs with fused BN+lrelu
  gemm2_kernel<<<1024, 256, 0, stream>>>(x, sA, hA, sB, hB, id_W, in_W, ident, hpre);
  // 3. mid-BN stats -> affine
  stats_affine_kernel<<<WIDTH / 4, 256, 0, stream>>>(hpre, WIDTH, mid_g, mid_b, sH, hH);
  // 4. fused aggregation + branch GEMMs (mid-BN applied at gather)
  AggP a0{src1, w1, W1, 32, 0};
  AggP a1{src2, w2, W2, 16, 32};
  AggP a2{src3, w3, W3, 16, 48};
  agg3_kernel<<<dim3(N_NODES, 3), 256, 0, stream>>>(a0, a1, a2, rowp, hpre, sH, hH, catb);
  // 5. out-BN stats -> affine
  stats_affine_kernel<<<WIDTH / 4, 256, 0, stream>>>(catb, WIDTH, out_g, out_b, sC, hC);
  // 6. final GEMM + residual
  final_kernel<<<N_NODES / 8, 256, 0, stream>>>(catb, sC, hC, out_W, ident, (float*)d_out);
}